// Round 3
// baseline (14470.006 us; speedup 1.0000x reference)
//
#include <hip/hip_runtime.h>
#include <math.h>

// NER BiLSTM-CRF on MI355X — persistent-kernel recurrence.
// fp32 throughout (Viterbi argmax flips are fatal: tags threshold 4.82, range 0..8).
//
// Structure: 256 blocks = 2 dir x 32 unit-groups(8 hidden units) x 4 batch-groups(16 b).
// One block/CU (77 KB LDS -> full residency guaranteed). Whh slice in VGPRs,
// Wih slice in LDS, gx computed on the fly. h exchanged via global (parity
// double buffer) with per-(dir,bg) 32-block monotonic barriers; h loads use
// sc0 sc1 (device-coherent across XCDs). c is thread-private.
//
// ws layout:
//   h_glob [2 par][2 d][4 bg][256 u][16 b] f32   262144 B   @ 0
//   cnts   8 counters, 128 B stride              4096 B     @ 262144
//   h_hist [64 b][512 l][512 h] f32              67108864 B @ 266240
//   em     [512][64][9] f32                      1179648 B  @ 67375104
//   last_tag [64] i32                            256 B      @ 68554752
//   hist   [64][512][9] u8                       294912 B   @ 68555008

#define Bv 64
#define Lv 512

__device__ __forceinline__ float sigmoidf_(float x) { return 1.0f / (1.0f + expf(-x)); }

__global__ __launch_bounds__(256, 1) void lstm_persist(
    const int* __restrict__ x, const float* __restrict__ embed,
    const float* __restrict__ Wih_f, const float* __restrict__ Whh_f, const float* __restrict__ bf,
    const float* __restrict__ Wih_b, const float* __restrict__ Whh_b, const float* __restrict__ bb_,
    float* __restrict__ h_glob, int* __restrict__ cnts, float* __restrict__ h_hist)
{
    const int bid = blockIdx.x;
    const int d  = bid >> 7;          // direction
    const int ug = (bid >> 2) & 31;   // unit group (8 units)
    const int bg = bid & 3;           // batch group (16 batches)
    const int tid = threadIdx.x;
    const int u0 = ug * 8;
    const int b0 = bg * 16;

    const float* Wih  = d ? Wih_b : Wih_f;
    const float* Whh  = d ? Whh_b : Whh_f;
    const float* bias = d ? bb_   : bf;

    // thread tiling: tid = ks*32 + tr*4 + tb
    //   ks: k-segment (32 k each), tr: row-tile (rows tr+8i), tb: batch-tile (b tb+4u)
    const int ks = tid >> 5;
    const int tr = (tid >> 2) & 7;
    const int tb = tid & 3;
    const int k0 = ks * 32;

    __shared__ float wih_lds[32][260];
    __shared__ float h_lds[16][260];
    __shared__ float emb_lds[16][260];
    __shared__ float parts[4][32][16];
    __shared__ float gates[32][16];
    __shared__ float bias_lds[32];

    // ---- stage Wih slice to LDS: row r = g*8+j  <-  Wih[g*256+u0+j][*] ----
    {
        const int row = tid >> 3;     // 0..31
        const int seg = tid & 7;      // 0..7 (32 floats each)
        const int g = row >> 3, j = row & 7;
        const float4* src = reinterpret_cast<const float4*>(
            Wih + ((size_t)(g * 256 + u0 + j)) * 256 + seg * 32);
        float4* dst = reinterpret_cast<float4*>(&wih_lds[row][seg * 32]);
        #pragma unroll
        for (int q = 0; q < 8; ++q) dst[q] = src[q];
    }
    if (tid < 32) bias_lds[tid] = bias[(tid >> 3) * 256 + u0 + (tid & 7)];

    // ---- Whh slice to registers: rows {tr+8i}, k window [k0, k0+32) ----
    float4 whh[4][8];
    #pragma unroll
    for (int i = 0; i < 4; ++i) {
        const float* wr = Whh + ((size_t)(i * 256 + u0 + tr)) * 256 + k0;
        #pragma unroll
        for (int m = 0; m < 8; ++m) whh[i][m] = *reinterpret_cast<const float4*>(wr + 4 * m);
    }

    float creg = 0.f;   // c for pointwise thread (tid<128): unit u0+(tid&7), batch b0+(tid>>3)
    int* cnt_ptr = cnts + (d * 4 + bg) * 32;

    for (int tt = 0; tt < Lv; ++tt) {
        const int t_eff = d ? (Lv - 1 - tt) : tt;
        const int par = tt & 1;
        __syncthreads();   // previous step's LDS uses complete

        // ---- stage embedding rows for this step ----
        {
            const int b = tid >> 4;       // 0..15
            const int cseg = tid & 15;    // 16 floats each
            const int xv = x[(b0 + b) * Lv + t_eff];
            const float4* src = reinterpret_cast<const float4*>(
                embed + (size_t)xv * 256 + cseg * 16);
            float4 e0 = src[0], e1 = src[1], e2 = src[2], e3 = src[3];
            float4* dstp = reinterpret_cast<float4*>(&emb_lds[b][cseg * 16]);
            dstp[0] = e0; dstp[1] = e1; dstp[2] = e2; dstp[3] = e3;
        }
        __syncthreads();

        float acc[4][4];
        #pragma unroll
        for (int i = 0; i < 4; ++i)
            #pragma unroll
            for (int u = 0; u < 4; ++u) acc[i][u] = 0.f;

        // ---- gx dot: Wih(lds) . emb(lds), K slice [k0,k0+32) ----
        #pragma unroll
        for (int m = 0; m < 8; ++m) {
            float4 ev[4];
            #pragma unroll
            for (int u = 0; u < 4; ++u)
                ev[u] = *reinterpret_cast<const float4*>(&emb_lds[tb + 4 * u][k0 + 4 * m]);
            #pragma unroll
            for (int i = 0; i < 4; ++i) {
                float4 wv = *reinterpret_cast<const float4*>(&wih_lds[tr + 8 * i][k0 + 4 * m]);
                #pragma unroll
                for (int u = 0; u < 4; ++u)
                    acc[i][u] += wv.x * ev[u].x + wv.y * ev[u].y + wv.z * ev[u].z + wv.w * ev[u].w;
            }
        }

        // ---- group barrier: wait until h^(tt) fully written ----
        if (tid == 0 && tt > 0) {
            const int target = 32 * tt;
            int it = 0;
            while (__hip_atomic_load(cnt_ptr, __ATOMIC_ACQUIRE, __HIP_MEMORY_SCOPE_AGENT) < target) {
                __builtin_amdgcn_s_sleep(2);
                if (++it > (1 << 24)) break;   // failsafe (never hit when resident)
            }
        }
        __syncthreads();

        if (tt > 0) {
            // ---- load h^(tt) (device-coherent) -> h_lds[b][u] ----
            const float* hs = h_glob + ((size_t)par * 8 + d * 4 + bg) * 4096 + tid * 16;
            float4 a0, a1, a2, a3;
            asm volatile(
                "global_load_dwordx4 %0, %4, off sc0 sc1\n\t"
                "global_load_dwordx4 %1, %4, off offset:16 sc0 sc1\n\t"
                "global_load_dwordx4 %2, %4, off offset:32 sc0 sc1\n\t"
                "global_load_dwordx4 %3, %4, off offset:48 sc0 sc1\n\t"
                "s_waitcnt vmcnt(0)"
                : "=v"(a0), "=v"(a1), "=v"(a2), "=v"(a3)
                : "v"(hs) : "memory");
            __builtin_amdgcn_sched_barrier(0);
            const int u = tid;   // thread holds h[u][b: 0..15]
            h_lds[ 0][u] = a0.x; h_lds[ 1][u] = a0.y; h_lds[ 2][u] = a0.z; h_lds[ 3][u] = a0.w;
            h_lds[ 4][u] = a1.x; h_lds[ 5][u] = a1.y; h_lds[ 6][u] = a1.z; h_lds[ 7][u] = a1.w;
            h_lds[ 8][u] = a2.x; h_lds[ 9][u] = a2.y; h_lds[10][u] = a2.z; h_lds[11][u] = a2.w;
            h_lds[12][u] = a3.x; h_lds[13][u] = a3.y; h_lds[14][u] = a3.z; h_lds[15][u] = a3.w;
        }
        __syncthreads();

        if (tt > 0) {
            // ---- recurrence dot: Whh(reg) . h(lds) ----
            #pragma unroll
            for (int m = 0; m < 8; ++m) {
                float4 hv[4];
                #pragma unroll
                for (int u = 0; u < 4; ++u)
                    hv[u] = *reinterpret_cast<const float4*>(&h_lds[tb + 4 * u][k0 + 4 * m]);
                #pragma unroll
                for (int i = 0; i < 4; ++i) {
                    float4 wv = whh[i][m];
                    #pragma unroll
                    for (int u = 0; u < 4; ++u)
                        acc[i][u] += wv.x * hv[u].x + wv.y * hv[u].y + wv.z * hv[u].z + wv.w * hv[u].w;
                }
            }
        }

        // ---- reduce over ksegs: shfl pairs (lane bit 5) then LDS over 4 waves ----
        #pragma unroll
        for (int i = 0; i < 4; ++i)
            #pragma unroll
            for (int u = 0; u < 4; ++u)
                acc[i][u] += __shfl_xor(acc[i][u], 32);
        if ((tid & 32) == 0) {
            const int w = tid >> 6;
            #pragma unroll
            for (int i = 0; i < 4; ++i)
                #pragma unroll
                for (int u = 0; u < 4; ++u)
                    parts[w][tr + 8 * i][tb + 4 * u] = acc[i][u];
        }
        __syncthreads();
        #pragma unroll
        for (int half = 0; half < 2; ++half) {
            const int o = tid + half * 256;
            const int r = o >> 4, b = o & 15;
            gates[r][b] = parts[0][r][b] + parts[1][r][b] + parts[2][r][b] + parts[3][r][b]
                        + bias_lds[r];
        }
        __syncthreads();

        // ---- pointwise LSTM update (gate rows: i=j, f=8+j, g=16+j, o=24+j) ----
        if (tid < 128) {
            const int j  = tid & 7;
            const int bb = tid >> 3;
            const float gi = gates[     j][bb];
            const float gf = gates[ 8 + j][bb];
            const float gg = gates[16 + j][bb];
            const float go = gates[24 + j][bb];
            creg = sigmoidf_(gf) * creg + sigmoidf_(gi) * tanhf(gg);
            const float h = sigmoidf_(go) * tanhf(creg);
            float* dst = h_glob + ((size_t)(par ^ 1) * 8 + d * 4 + bg) * 4096
                       + (size_t)(u0 + j) * 16 + bb;
            __hip_atomic_store(dst, h, __ATOMIC_RELAXED, __HIP_MEMORY_SCOPE_AGENT);
            h_hist[((size_t)(b0 + bb) * Lv + t_eff) * 512 + d * 256 + u0 + j] = h;
        }
        __threadfence();
        __syncthreads();
        if (tid == 0)
            __hip_atomic_fetch_add(cnt_ptr, 1, __ATOMIC_RELEASE, __HIP_MEMORY_SCOPE_AGENT);
    }
}

// emissions: em[l][b][j] = dot(h_hist[b][l][:512], Wout[j]) + bout[j]
__global__ __launch_bounds__(256) void emis_kernel(
    const float* __restrict__ h_hist, const float* __restrict__ Wout,
    const float* __restrict__ bout, float* __restrict__ em)
{
    const int l  = blockIdx.x >> 2;
    const int bg = blockIdx.x & 3;
    const int tid = threadIdx.x;
    __shared__ float w_lds[9][516];
    __shared__ float h_ldsx[16][512];

    for (int i = tid; i < 9 * 512; i += 256) w_lds[i >> 9][i & 511] = Wout[i];
    for (int i = tid; i < 16 * 128; i += 256) {
        const int bb = i >> 7; const int k = (i & 127) * 4;
        *reinterpret_cast<float4*>(&h_ldsx[bb][k]) =
            *reinterpret_cast<const float4*>(&h_hist[((size_t)(bg * 16 + bb) * 512 + l) * 512 + k]);
    }
    __syncthreads();

    const int bb = tid >> 4;
    const int j = tid & 15;
    if (j < 9) {
        float acc = bout[j];
        #pragma unroll 4
        for (int k = 0; k < 512; k += 4) {
            float4 hv = *reinterpret_cast<const float4*>(&h_ldsx[bb][k]);
            float4 wv = *reinterpret_cast<const float4*>(&w_lds[j][k]);
            acc += hv.x * wv.x + hv.y * wv.y + hv.z * wv.z + hv.w * wv.w;
        }
        em[((size_t)l * 64 + bg * 16 + bb) * 9 + j] = acc;
    }
}

__global__ __launch_bounds__(576) void viterbi_fwd(
    const float* __restrict__ em, const float* __restrict__ start,
    const float* __restrict__ trans, const float* __restrict__ endt,
    unsigned char* __restrict__ hist, int* __restrict__ last_tag,
    float* __restrict__ out_best)
{
    const int tid = threadIdx.x;
    const int b = tid / 9;
    const int j = tid - b * 9;
    __shared__ float sc[2][64][9];
    float t9[9];
    #pragma unroll
    for (int i = 0; i < 9; ++i) t9[i] = trans[i * 9 + j];

    sc[0][b][j] = start[j] + em[tid];
    __syncthreads();
    for (int t = 1; t < 512; ++t) {
        const int cur = t & 1, prv = cur ^ 1;
        float best = -1e30f; int arg = 0;
        #pragma unroll
        for (int i = 0; i < 9; ++i) {
            float v = sc[prv][b][i] + t9[i];
            if (v > best) { best = v; arg = i; }
        }
        best += em[(t * 64 + b) * 9 + j];
        sc[cur][b][j] = best;
        hist[((size_t)b * 512 + t) * 9 + j] = (unsigned char)arg;
        __syncthreads();
    }
    sc[1][b][j] += endt[j];
    __syncthreads();
    if (j == 0) {
        float best = -1e30f; int arg = 0;
        #pragma unroll
        for (int i = 0; i < 9; ++i) {
            float v = sc[1][b][i];
            if (v > best) { best = v; arg = i; }
        }
        out_best[b] = best;
        last_tag[b] = arg;
    }
}

__global__ __launch_bounds__(256) void backtrack(
    const unsigned char* __restrict__ hist, const int* __restrict__ last_tag,
    float* __restrict__ out_tags)
{
    const int b = blockIdx.x;
    const int tid = threadIdx.x;
    __shared__ __align__(16) unsigned char hl[512 * 9];
    const uint4* src = reinterpret_cast<const uint4*>(hist + (size_t)b * 512 * 9);
    uint4* dst = reinterpret_cast<uint4*>(hl);
    for (int i = tid; i < 512 * 9 / 16; i += 256) dst[i] = src[i];
    __syncthreads();
    if (tid == 0) {
        int tag = last_tag[b];
        out_tags[b * 512 + 511] = (float)tag;
        for (int t = 511; t >= 1; --t) {
            tag = hl[t * 9 + tag];
            out_tags[b * 512 + t - 1] = (float)tag;
        }
    }
}

extern "C" void kernel_launch(void* const* d_in, const int* in_sizes, int n_in,
                              void* d_out, int out_size, void* d_ws, size_t ws_size,
                              hipStream_t stream)
{
    const int*   x     = (const int*)d_in[0];
    const float* embed = (const float*)d_in[1];
    const float* Wih_f = (const float*)d_in[2];
    const float* Whh_f = (const float*)d_in[3];
    const float* bf    = (const float*)d_in[4];
    const float* Wih_b = (const float*)d_in[5];
    const float* Whh_b = (const float*)d_in[6];
    const float* bb    = (const float*)d_in[7];
    const float* Wout  = (const float*)d_in[8];
    const float* bout  = (const float*)d_in[9];
    const float* start = (const float*)d_in[10];
    const float* trans = (const float*)d_in[11];
    const float* endt  = (const float*)d_in[12];

    char* ws = (char*)d_ws;
    float* h_glob = (float*)ws;                                   // 262144 B
    int*   cnts   = (int*)(ws + 262144);                          // 4096 B
    float* h_hist = (float*)(ws + 266240);                        // 67108864 B
    float* em     = (float*)(ws + 266240 + 67108864);             // 1179648 B
    int*   last_tag = (int*)(ws + 67375104 + 1179648);            // @68554752
    unsigned char* hist = (unsigned char*)(ws + 68554752 + 256);  // @68555008

    float* out = (float*)d_out;   // [64*512 tags][64 best], all f32

    hipMemsetAsync(cnts, 0, 4096, stream);   // reset group barriers each call

    lstm_persist<<<256, 256, 0, stream>>>(x, embed, Wih_f, Whh_f, bf,
                                          Wih_b, Whh_b, bb,
                                          h_glob, cnts, h_hist);
    emis_kernel<<<2048, 256, 0, stream>>>(h_hist, Wout, bout, em);
    viterbi_fwd<<<1, 576, 0, stream>>>(em, start, trans, endt, hist, last_tag, out + 64 * 512);
    backtrack<<<64, 256, 0, stream>>>(hist, last_tag, out);
}

// Round 4
// 3120.814 us; speedup vs baseline: 4.6366x; 4.6366x over previous
//
#include <hip/hip_runtime.h>
#include <math.h>

// NER BiLSTM-CRF on MI355X — persistent-kernel recurrence, fence-free coherence.
// fp32 throughout (Viterbi argmax flips are fatal: tags threshold 4.82, range 0..8).
//
// 256 blocks = 2 dir x 32 unit-groups(8 units) x 4 batch-groups(16 b), 1 block/CU
// (94 KB LDS forces full residency -> spin-sync deadlock-safe).
// Cross-block h exchange: ALL h_glob/cnts accesses bypass L1+L2 (sc0 sc1), so the
// L3 (die-level, shared) is the coherence point and no cache fences are needed.
// Release: sc0sc1 stores + vmcnt(0) + syncthreads + relaxed agent atomic add.
// Acquire: relaxed sc0sc1 poll load, then sc0sc1 data loads. NO threadfence,
// NO acquire/release atomics (those emit whole-L2 writeback/invalidate per call
// on gfx950 — that was round 3's 27us/step).
//
// ws layout:
//   h_glob [2 par][2 d][4 bg][256 u][16 b] f32   262144 B   @ 0
//   cnts   8 counters, 128 B stride              4096 B     @ 262144
//   h_hist [64 b][512 l][512 h] f32              67108864 B @ 266240
//   em     [512][64][9] f32                      1179648 B  @ 67375104
//   last_tag [64] i32                            256 B      @ 68554752
//   hist   [64][512][9] u8                       294912 B   @ 68555008

#define Bv 64
#define Lv 512

__device__ __forceinline__ float sigmoidf_(float x) { return 1.0f / (1.0f + expf(-x)); }

__global__ __launch_bounds__(256, 1) void lstm_persist(
    const int* __restrict__ x, const float* __restrict__ embed,
    const float* __restrict__ Wih_f, const float* __restrict__ Whh_f, const float* __restrict__ bf,
    const float* __restrict__ Wih_b, const float* __restrict__ Whh_b, const float* __restrict__ bb_,
    float* __restrict__ h_glob, int* __restrict__ cnts, float* __restrict__ h_hist)
{
    const int bid = blockIdx.x;
    const int d  = bid >> 7;          // direction
    const int ug = (bid >> 2) & 31;   // unit group (8 units)
    const int bg = bid & 3;           // batch group (16 batches)
    const int tid = threadIdx.x;
    const int u0 = ug * 8;
    const int b0 = bg * 16;

    const float* Wih  = d ? Wih_b : Wih_f;
    const float* Whh  = d ? Whh_b : Whh_f;
    const float* bias = d ? bb_   : bf;

    // thread tiling: tid = ks*32 + tr*4 + tb
    const int ks = tid >> 5;
    const int tr = (tid >> 2) & 7;
    const int tb = tid & 3;
    const int k0 = ks * 32;

    __shared__ float wih_lds[32][260];
    __shared__ float h_lds[16][260];
    __shared__ float emb_lds[2][16][260];
    __shared__ float parts[4][32][16];
    __shared__ float gates[32][16];
    __shared__ float bias_lds[32];

    // ---- stage Wih slice to LDS ----
    {
        const int row = tid >> 3;     // 0..31
        const int seg = tid & 7;      // 32 floats each
        const int g = row >> 3, j = row & 7;
        const float4* src = reinterpret_cast<const float4*>(
            Wih + ((size_t)(g * 256 + u0 + j)) * 256 + seg * 32);
        float4* dst = reinterpret_cast<float4*>(&wih_lds[row][seg * 32]);
        #pragma unroll
        for (int q = 0; q < 8; ++q) dst[q] = src[q];
    }
    if (tid < 32) bias_lds[tid] = bias[(tid >> 3) * 256 + u0 + (tid & 7)];

    // ---- Whh slice to registers: rows {tr+8i}, k window [k0, k0+32) ----
    float4 whh[4][8];
    #pragma unroll
    for (int i = 0; i < 4; ++i) {
        const float* wr = Whh + ((size_t)(i * 256 + u0 + tr)) * 256 + k0;
        #pragma unroll
        for (int m = 0; m < 8; ++m) whh[i][m] = *reinterpret_cast<const float4*>(wr + 4 * m);
    }

    float creg = 0.f;
    int* cnt_ptr = cnts + (d * 4 + bg) * 32;

    // prologue: stage embedding for step 0 into buffer 0
    {
        const int b = tid >> 4;
        const int cseg = tid & 15;
        const int t_eff0 = d ? (Lv - 1) : 0;
        const int xv = x[(b0 + b) * Lv + t_eff0];
        const float4* src = reinterpret_cast<const float4*>(embed + (size_t)xv * 256 + cseg * 16);
        float4* dstp = reinterpret_cast<float4*>(&emb_lds[0][b][cseg * 16]);
        dstp[0] = src[0]; dstp[1] = src[1]; dstp[2] = src[2]; dstp[3] = src[3];
    }
    __syncthreads();

    for (int tt = 0; tt < Lv; ++tt) {
        const int par = tt & 1;       // also the emb buffer parity

        float acc[4][4];
        #pragma unroll
        for (int i = 0; i < 4; ++i)
            #pragma unroll
            for (int u = 0; u < 4; ++u) acc[i][u] = 0.f;

        // ---- gx dot: Wih(lds) . emb(lds[par]), K slice [k0,k0+32) ----
        #pragma unroll
        for (int m = 0; m < 8; ++m) {
            float4 ev[4];
            #pragma unroll
            for (int u = 0; u < 4; ++u)
                ev[u] = *reinterpret_cast<const float4*>(&emb_lds[par][tb + 4 * u][k0 + 4 * m]);
            #pragma unroll
            for (int i = 0; i < 4; ++i) {
                float4 wv = *reinterpret_cast<const float4*>(&wih_lds[tr + 8 * i][k0 + 4 * m]);
                #pragma unroll
                for (int u = 0; u < 4; ++u)
                    acc[i][u] += wv.x * ev[u].x + wv.y * ev[u].y + wv.z * ev[u].z + wv.w * ev[u].w;
            }
        }

        // ---- stage embedding for step tt+1 (overlaps the spin below) ----
        if (tt + 1 < Lv) {
            const int b = tid >> 4;
            const int cseg = tid & 15;
            const int t_eff1 = d ? (Lv - 2 - tt) : (tt + 1);
            const int xv = x[(b0 + b) * Lv + t_eff1];
            const float4* src = reinterpret_cast<const float4*>(embed + (size_t)xv * 256 + cseg * 16);
            float4 e0 = src[0], e1 = src[1], e2 = src[2], e3 = src[3];
            float4* dstp = reinterpret_cast<float4*>(&emb_lds[par ^ 1][b][cseg * 16]);
            dstp[0] = e0; dstp[1] = e1; dstp[2] = e2; dstp[3] = e3;
        }

        // ---- group barrier: relaxed sc0sc1 poll (no cache invalidates) ----
        if (tid == 0 && tt > 0) {
            const int target = 32 * tt;
            int it = 0, v;
            for (;;) {
                asm volatile("global_load_dword %0, %1, off sc0 sc1\n\t"
                             "s_waitcnt vmcnt(0)"
                             : "=v"(v) : "v"(cnt_ptr) : "memory");
                if (v >= target) break;
                __builtin_amdgcn_s_sleep(1);
                if (++it > (1 << 24)) break;   // failsafe (never hit when resident)
            }
        }
        __syncthreads();   // barrier passed + emb[par^1] writes complete

        if (tt > 0) {
            // ---- load h^(tt) from L3 (sc0sc1) -> h_lds[b][u] ----
            const float* hs = h_glob + ((size_t)par * 8 + d * 4 + bg) * 4096 + tid * 16;
            float4 a0, a1, a2, a3;
            asm volatile(
                "global_load_dwordx4 %0, %4, off sc0 sc1\n\t"
                "global_load_dwordx4 %1, %4, off offset:16 sc0 sc1\n\t"
                "global_load_dwordx4 %2, %4, off offset:32 sc0 sc1\n\t"
                "global_load_dwordx4 %3, %4, off offset:48 sc0 sc1\n\t"
                "s_waitcnt vmcnt(0)"
                : "=v"(a0), "=v"(a1), "=v"(a2), "=v"(a3)
                : "v"(hs) : "memory");
            __builtin_amdgcn_sched_barrier(0);
            const int u = tid;
            h_lds[ 0][u] = a0.x; h_lds[ 1][u] = a0.y; h_lds[ 2][u] = a0.z; h_lds[ 3][u] = a0.w;
            h_lds[ 4][u] = a1.x; h_lds[ 5][u] = a1.y; h_lds[ 6][u] = a1.z; h_lds[ 7][u] = a1.w;
            h_lds[ 8][u] = a2.x; h_lds[ 9][u] = a2.y; h_lds[10][u] = a2.z; h_lds[11][u] = a2.w;
            h_lds[12][u] = a3.x; h_lds[13][u] = a3.y; h_lds[14][u] = a3.z; h_lds[15][u] = a3.w;
        }
        __syncthreads();

        if (tt > 0) {
            // ---- recurrence dot: Whh(reg) . h(lds) ----
            #pragma unroll
            for (int m = 0; m < 8; ++m) {
                float4 hv[4];
                #pragma unroll
                for (int u = 0; u < 4; ++u)
                    hv[u] = *reinterpret_cast<const float4*>(&h_lds[tb + 4 * u][k0 + 4 * m]);
                #pragma unroll
                for (int i = 0; i < 4; ++i) {
                    float4 wv = whh[i][m];
                    #pragma unroll
                    for (int u = 0; u < 4; ++u)
                        acc[i][u] += wv.x * hv[u].x + wv.y * hv[u].y + wv.z * hv[u].z + wv.w * hv[u].w;
                }
            }
        }

        // ---- reduce over ksegs ----
        #pragma unroll
        for (int i = 0; i < 4; ++i)
            #pragma unroll
            for (int u = 0; u < 4; ++u)
                acc[i][u] += __shfl_xor(acc[i][u], 32);
        if ((tid & 32) == 0) {
            const int w = tid >> 6;
            #pragma unroll
            for (int i = 0; i < 4; ++i)
                #pragma unroll
                for (int u = 0; u < 4; ++u)
                    parts[w][tr + 8 * i][tb + 4 * u] = acc[i][u];
        }
        __syncthreads();
        #pragma unroll
        for (int half = 0; half < 2; ++half) {
            const int o = tid + half * 256;
            const int r = o >> 4, b = o & 15;
            gates[r][b] = parts[0][r][b] + parts[1][r][b] + parts[2][r][b] + parts[3][r][b]
                        + bias_lds[r];
        }
        __syncthreads();

        // ---- pointwise LSTM update; h store bypasses caches (sc0 sc1) ----
        if (tid < 128) {
            const int j  = tid & 7;
            const int bb = tid >> 3;
            const int t_eff = d ? (Lv - 1 - tt) : tt;
            const float gi = gates[     j][bb];
            const float gf = gates[ 8 + j][bb];
            const float gg = gates[16 + j][bb];
            const float go = gates[24 + j][bb];
            creg = sigmoidf_(gf) * creg + sigmoidf_(gi) * tanhf(gg);
            const float h = sigmoidf_(go) * tanhf(creg);
            float* dst = h_glob + ((size_t)(par ^ 1) * 8 + d * 4 + bg) * 4096
                       + (size_t)(u0 + j) * 16 + bb;
            asm volatile("global_store_dword %0, %1, off sc0 sc1"
                         :: "v"(dst), "v"(h) : "memory");
            h_hist[((size_t)(b0 + bb) * Lv + t_eff) * 512 + d * 256 + u0 + j] = h;
        }
        // release: wait own stores reached coherence point, then count
        asm volatile("s_waitcnt vmcnt(0)" ::: "memory");
        __syncthreads();
        if (tid == 0)
            __hip_atomic_fetch_add(cnt_ptr, 1, __ATOMIC_RELAXED, __HIP_MEMORY_SCOPE_AGENT);
    }
}

// emissions: em[l][b][j] = dot(h_hist[b][l][:512], Wout[j]) + bout[j]
__global__ __launch_bounds__(256) void emis_kernel(
    const float* __restrict__ h_hist, const float* __restrict__ Wout,
    const float* __restrict__ bout, float* __restrict__ em)
{
    const int l  = blockIdx.x >> 2;
    const int bg = blockIdx.x & 3;
    const int tid = threadIdx.x;
    __shared__ float w_lds[9][516];
    __shared__ float h_ldsx[16][512];

    for (int i = tid; i < 9 * 512; i += 256) w_lds[i >> 9][i & 511] = Wout[i];
    for (int i = tid; i < 16 * 128; i += 256) {
        const int bb = i >> 7; const int k = (i & 127) * 4;
        *reinterpret_cast<float4*>(&h_ldsx[bb][k]) =
            *reinterpret_cast<const float4*>(&h_hist[((size_t)(bg * 16 + bb) * 512 + l) * 512 + k]);
    }
    __syncthreads();

    const int bb = tid >> 4;
    const int j = tid & 15;
    if (j < 9) {
        float acc = bout[j];
        #pragma unroll 4
        for (int k = 0; k < 512; k += 4) {
            float4 hv = *reinterpret_cast<const float4*>(&h_ldsx[bb][k]);
            float4 wv = *reinterpret_cast<const float4*>(&w_lds[j][k]);
            acc += hv.x * wv.x + hv.y * wv.y + hv.z * wv.z + hv.w * wv.w;
        }
        em[((size_t)l * 64 + bg * 16 + bb) * 9 + j] = acc;
    }
}

__global__ __launch_bounds__(576) void viterbi_fwd(
    const float* __restrict__ em, const float* __restrict__ start,
    const float* __restrict__ trans, const float* __restrict__ endt,
    unsigned char* __restrict__ hist, int* __restrict__ last_tag,
    float* __restrict__ out_best)
{
    const int tid = threadIdx.x;
    const int b = tid / 9;
    const int j = tid - b * 9;
    __shared__ float sc[2][64][9];
    float t9[9];
    #pragma unroll
    for (int i = 0; i < 9; ++i) t9[i] = trans[i * 9 + j];

    sc[0][b][j] = start[j] + em[tid];
    float emv = em[(64 + b) * 9 + j];          // em for t=1
    __syncthreads();
    for (int t = 1; t < 512; ++t) {
        float em_nxt = (t < 511) ? em[((t + 1) * 64 + b) * 9 + j] : 0.f;  // prefetch
        const int cur = t & 1, prv = cur ^ 1;
        float best = -1e30f; int arg = 0;
        #pragma unroll
        for (int i = 0; i < 9; ++i) {
            float v = sc[prv][b][i] + t9[i];
            if (v > best) { best = v; arg = i; }
        }
        best += emv;
        sc[cur][b][j] = best;
        hist[((size_t)b * 512 + t) * 9 + j] = (unsigned char)arg;
        __syncthreads();
        emv = em_nxt;
    }
    sc[1][b][j] += endt[j];
    __syncthreads();
    if (j == 0) {
        float best = -1e30f; int arg = 0;
        #pragma unroll
        for (int i = 0; i < 9; ++i) {
            float v = sc[1][b][i];
            if (v > best) { best = v; arg = i; }
        }
        out_best[b] = best;
        last_tag[b] = arg;
    }
}

__global__ __launch_bounds__(256) void backtrack(
    const unsigned char* __restrict__ hist, const int* __restrict__ last_tag,
    float* __restrict__ out_tags)
{
    const int b = blockIdx.x;
    const int tid = threadIdx.x;
    __shared__ __align__(16) unsigned char hl[512 * 9];
    const uint4* src = reinterpret_cast<const uint4*>(hist + (size_t)b * 512 * 9);
    uint4* dst = reinterpret_cast<uint4*>(hl);
    for (int i = tid; i < 512 * 9 / 16; i += 256) dst[i] = src[i];
    __syncthreads();
    if (tid == 0) {
        int tag = last_tag[b];
        out_tags[b * 512 + 511] = (float)tag;
        for (int t = 511; t >= 1; --t) {
            tag = hl[t * 9 + tag];
            out_tags[b * 512 + t - 1] = (float)tag;
        }
    }
}

extern "C" void kernel_launch(void* const* d_in, const int* in_sizes, int n_in,
                              void* d_out, int out_size, void* d_ws, size_t ws_size,
                              hipStream_t stream)
{
    const int*   x     = (const int*)d_in[0];
    const float* embed = (const float*)d_in[1];
    const float* Wih_f = (const float*)d_in[2];
    const float* Whh_f = (const float*)d_in[3];
    const float* bf    = (const float*)d_in[4];
    const float* Wih_b = (const float*)d_in[5];
    const float* Whh_b = (const float*)d_in[6];
    const float* bb    = (const float*)d_in[7];
    const float* Wout  = (const float*)d_in[8];
    const float* bout  = (const float*)d_in[9];
    const float* start = (const float*)d_in[10];
    const float* trans = (const float*)d_in[11];
    const float* endt  = (const float*)d_in[12];

    char* ws = (char*)d_ws;
    float* h_glob = (float*)ws;                                   // 262144 B
    int*   cnts   = (int*)(ws + 262144);                          // 4096 B
    float* h_hist = (float*)(ws + 266240);                        // 67108864 B
    float* em     = (float*)(ws + 266240 + 67108864);             // 1179648 B
    int*   last_tag = (int*)(ws + 67375104 + 1179648);            // @68554752
    unsigned char* hist = (unsigned char*)(ws + 68554752 + 256);  // @68555008

    float* out = (float*)d_out;   // [64*512 tags][64 best], all f32

    hipMemsetAsync(cnts, 0, 4096, stream);   // reset group barriers each call

    lstm_persist<<<256, 256, 0, stream>>>(x, embed, Wih_f, Whh_f, bf,
                                          Wih_b, Whh_b, bb,
                                          h_glob, cnts, h_hist);
    emis_kernel<<<2048, 256, 0, stream>>>(h_hist, Wout, bout, em);
    viterbi_fwd<<<1, 576, 0, stream>>>(em, start, trans, endt, hist, last_tag, out + 64 * 512);
    backtrack<<<64, 256, 0, stream>>>(hist, last_tag, out);
}

// Round 5
// 2851.906 us; speedup vs baseline: 5.0738x; 1.0943x over previous
//
#include <hip/hip_runtime.h>
#include <math.h>

// NER BiLSTM-CRF on MI355X — persistent recurrence, fence-free + atomic-free sync.
// fp32 throughout (Viterbi argmax flips are fatal: tags threshold 4.82, range 0..8).
//
// 256 blocks = 2 dir x 32 unit-groups(8 units) x 4 batch-groups(16 b), 1 block/CU
// (92 KB LDS forces full residency -> spin-sync deadlock-safe).
// Cross-block h exchange bypasses L1/L2 (sc0 sc1 -> L3 is the coherence point):
//   release: h stores sc0sc1 -> vmcnt(0) -> syncthreads -> tag[g][ug]=tt+1 (plain store sc0sc1)
//   acquire: each thread polls ONLY its own producer's tag (unit u=tid <- producer tid>>3),
//            then loads its 64B h chunk. No atomics (round-4's 32-way fetch_add to one
//            line serialized ~2-3k cyc/step), no fences, no sleep.
// Double-buffer safety: tag marks END of a block's step (after its h consumption),
// so step-t writes to buf[par^1] can't begin until every block finished step t-1 reads.
//
// ws layout:
//   h_glob [2 par][2 d * 4 bg][256 u][16 b] f32  262144 B   @ 0
//   tags   [8 g][32 ug] i32                      4096 B     @ 262144
//   h_hist [64 b][512 l][512 h] f32              67108864 B @ 266240
//   em     [512][64][9] f32                      1179648 B  @ 67375104
//   last_tag [64] i32                            256 B      @ 68554752
//   hist   [64][512][9] u8                       294912 B   @ 68555008

#define Bv 64
#define Lv 512

__device__ __forceinline__ float sigmoidf_(float x) { return 1.0f / (1.0f + expf(-x)); }

__global__ __launch_bounds__(256, 1) void lstm_persist(
    const int* __restrict__ x, const float* __restrict__ embed,
    const float* __restrict__ Wih_f, const float* __restrict__ Whh_f, const float* __restrict__ bf,
    const float* __restrict__ Wih_b, const float* __restrict__ Whh_b, const float* __restrict__ bb_,
    float* __restrict__ h_glob, int* __restrict__ tags, float* __restrict__ h_hist)
{
    const int bid = blockIdx.x;
    const int d  = bid >> 7;          // direction
    const int ug = (bid >> 2) & 31;   // unit group (8 units)
    const int bg = bid & 3;           // batch group (16 batches)
    const int g  = d * 4 + bg;        // sync group (32 blocks)
    const int tid = threadIdx.x;
    const int u0 = ug * 8;
    const int b0 = bg * 16;

    const float* Wih  = d ? Wih_b : Wih_f;
    const float* Whh  = d ? Whh_b : Whh_f;
    const float* bias = d ? bb_   : bf;

    // thread tiling for the dots: tid = ks*32 + tr*4 + tb
    const int ks = tid >> 5;
    const int tr = (tid >> 2) & 7;
    const int tb = tid & 3;
    const int k0 = ks * 32;

    __shared__ float wih_lds[32][260];
    __shared__ float h_lds[16][260];
    __shared__ float emb_lds[2][16][260];
    __shared__ float parts[4][32][17];
    __shared__ float bias_lds[32];

    // ---- stage Wih slice to LDS ----
    {
        const int row = tid >> 3;     // 0..31
        const int seg = tid & 7;      // 32 floats each
        const int gq = row >> 3, j = row & 7;
        const float4* src = reinterpret_cast<const float4*>(
            Wih + ((size_t)(gq * 256 + u0 + j)) * 256 + seg * 32);
        float4* dst = reinterpret_cast<float4*>(&wih_lds[row][seg * 32]);
        #pragma unroll
        for (int q = 0; q < 8; ++q) dst[q] = src[q];
    }
    if (tid < 32) bias_lds[tid] = bias[(tid >> 3) * 256 + u0 + (tid & 7)];

    // ---- Whh slice to registers: rows {tr+8i}, k window [k0, k0+32) ----
    float4 whh[4][8];
    #pragma unroll
    for (int i = 0; i < 4; ++i) {
        const float* wr = Whh + ((size_t)(i * 256 + u0 + tr)) * 256 + k0;
        #pragma unroll
        for (int m = 0; m < 8; ++m) whh[i][m] = *reinterpret_cast<const float4*>(wr + 4 * m);
    }

    float creg = 0.f;
    const int* my_tag = tags + g * 32 + (tid >> 3);     // producer of unit u=tid
    int* rel_tag = tags + g * 32 + ug;

    // prologue: stage embedding for step 0 into buffer 0
    {
        const int b = tid >> 4;
        const int cseg = tid & 15;
        const int t_eff0 = d ? (Lv - 1) : 0;
        const int xv = x[(b0 + b) * Lv + t_eff0];
        const float4* src = reinterpret_cast<const float4*>(embed + (size_t)xv * 256 + cseg * 16);
        float4* dstp = reinterpret_cast<float4*>(&emb_lds[0][b][cseg * 16]);
        dstp[0] = src[0]; dstp[1] = src[1]; dstp[2] = src[2]; dstp[3] = src[3];
    }
    __syncthreads();

    for (int tt = 0; tt < Lv; ++tt) {
        const int par = tt & 1;       // emb buffer + h_glob parity

        float acc[4][4];
        #pragma unroll
        for (int i = 0; i < 4; ++i)
            #pragma unroll
            for (int u = 0; u < 4; ++u) acc[i][u] = 0.f;

        // ---- gx dot: Wih(lds) . emb(lds[par]), K slice [k0,k0+32) ----
        #pragma unroll
        for (int m = 0; m < 8; ++m) {
            float4 ev[4];
            #pragma unroll
            for (int u = 0; u < 4; ++u)
                ev[u] = *reinterpret_cast<const float4*>(&emb_lds[par][tb + 4 * u][k0 + 4 * m]);
            #pragma unroll
            for (int i = 0; i < 4; ++i) {
                float4 wv = *reinterpret_cast<const float4*>(&wih_lds[tr + 8 * i][k0 + 4 * m]);
                #pragma unroll
                for (int u = 0; u < 4; ++u)
                    acc[i][u] += wv.x * ev[u].x + wv.y * ev[u].y + wv.z * ev[u].z + wv.w * ev[u].w;
            }
        }

        // ---- stage embedding for step tt+1 (overlaps the tag wait below) ----
        if (tt + 1 < Lv) {
            const int b = tid >> 4;
            const int cseg = tid & 15;
            const int t_eff1 = d ? (Lv - 2 - tt) : (tt + 1);
            const int xv = x[(b0 + b) * Lv + t_eff1];
            const float4* src = reinterpret_cast<const float4*>(embed + (size_t)xv * 256 + cseg * 16);
            float4 e0 = src[0], e1 = src[1], e2 = src[2], e3 = src[3];
            float4* dstp = reinterpret_cast<float4*>(&emb_lds[par ^ 1][b][cseg * 16]);
            dstp[0] = e0; dstp[1] = e1; dstp[2] = e2; dstp[3] = e3;
        }

        if (tt > 0) {
            // ---- per-thread: wait own producer's tag, then load own h chunk ----
            int v, it = 0;
            for (;;) {
                asm volatile("global_load_dword %0, %1, off sc0 sc1\n\t"
                             "s_waitcnt vmcnt(0)"
                             : "=v"(v) : "v"(my_tag) : "memory");
                if (v >= tt) break;
                if (++it > (1 << 22)) break;   // failsafe (never hit when resident)
            }
            const float* hs = h_glob + ((size_t)par * 8 + g) * 4096 + tid * 16;
            float4 a0, a1, a2, a3;
            asm volatile(
                "global_load_dwordx4 %0, %4, off sc0 sc1\n\t"
                "global_load_dwordx4 %1, %4, off offset:16 sc0 sc1\n\t"
                "global_load_dwordx4 %2, %4, off offset:32 sc0 sc1\n\t"
                "global_load_dwordx4 %3, %4, off offset:48 sc0 sc1\n\t"
                "s_waitcnt vmcnt(0)"
                : "=v"(a0), "=v"(a1), "=v"(a2), "=v"(a3)
                : "v"(hs) : "memory");
            __builtin_amdgcn_sched_barrier(0);
            const int u = tid;   // thread holds h[u][b: 0..15]
            h_lds[ 0][u] = a0.x; h_lds[ 1][u] = a0.y; h_lds[ 2][u] = a0.z; h_lds[ 3][u] = a0.w;
            h_lds[ 4][u] = a1.x; h_lds[ 5][u] = a1.y; h_lds[ 6][u] = a1.z; h_lds[ 7][u] = a1.w;
            h_lds[ 8][u] = a2.x; h_lds[ 9][u] = a2.y; h_lds[10][u] = a2.z; h_lds[11][u] = a2.w;
            h_lds[12][u] = a3.x; h_lds[13][u] = a3.y; h_lds[14][u] = a3.z; h_lds[15][u] = a3.w;
        }
        __syncthreads();   // h_lds complete + emb[par^1] writes complete

        if (tt > 0) {
            // ---- recurrence dot: Whh(reg) . h(lds) ----
            #pragma unroll
            for (int m = 0; m < 8; ++m) {
                float4 hv[4];
                #pragma unroll
                for (int u = 0; u < 4; ++u)
                    hv[u] = *reinterpret_cast<const float4*>(&h_lds[tb + 4 * u][k0 + 4 * m]);
                #pragma unroll
                for (int i = 0; i < 4; ++i) {
                    float4 wv = whh[i][m];
                    #pragma unroll
                    for (int u = 0; u < 4; ++u)
                        acc[i][u] += wv.x * hv[u].x + wv.y * hv[u].y + wv.z * hv[u].z + wv.w * hv[u].w;
                }
            }
        }

        // ---- reduce over ksegs: shfl (bit5) then parts over 4 waves ----
        #pragma unroll
        for (int i = 0; i < 4; ++i)
            #pragma unroll
            for (int u = 0; u < 4; ++u)
                acc[i][u] += __shfl_xor(acc[i][u], 32);
        if ((tid & 32) == 0) {
            const int w = tid >> 6;
            #pragma unroll
            for (int i = 0; i < 4; ++i)
                #pragma unroll
                for (int u = 0; u < 4; ++u)
                    parts[w][tr + 8 * i][tb + 4 * u] = acc[i][u];
        }
        __syncthreads();

        // ---- pointwise LSTM update; reads parts directly (no gates stage) ----
        if (tid < 128) {
            const int j  = tid & 7;
            const int bb = tid >> 3;
            const int t_eff = d ? (Lv - 1 - tt) : tt;
            float gv[4];
            #pragma unroll
            for (int q = 0; q < 4; ++q) {
                const int r = q * 8 + j;
                gv[q] = parts[0][r][bb] + parts[1][r][bb] + parts[2][r][bb] + parts[3][r][bb]
                      + bias_lds[r];
            }
            creg = sigmoidf_(gv[1]) * creg + sigmoidf_(gv[0]) * tanhf(gv[2]);
            const float h = sigmoidf_(gv[3]) * tanhf(creg);
            float* dst = h_glob + ((size_t)(par ^ 1) * 8 + g) * 4096
                       + (size_t)(u0 + j) * 16 + bb;
            asm volatile("global_store_dword %0, %1, off sc0 sc1"
                         :: "v"(dst), "v"(h) : "memory");
            h_hist[((size_t)(b0 + bb) * Lv + t_eff) * 512 + d * 256 + u0 + j] = h;
        }
        // release: own stores at coherence point, all threads done, then tag
        asm volatile("s_waitcnt vmcnt(0)" ::: "memory");
        __syncthreads();
        if (tid == 0) {
            int val = tt + 1;
            asm volatile("global_store_dword %0, %1, off sc0 sc1"
                         :: "v"(rel_tag), "v"(val) : "memory");
        }
    }
}

// emissions: em[l][b][j] = dot(h_hist[b][l][:512], Wout[j]) + bout[j]
__global__ __launch_bounds__(256) void emis_kernel(
    const float* __restrict__ h_hist, const float* __restrict__ Wout,
    const float* __restrict__ bout, float* __restrict__ em)
{
    const int l  = blockIdx.x >> 2;
    const int bg = blockIdx.x & 3;
    const int tid = threadIdx.x;
    __shared__ float w_lds[9][516];
    __shared__ float h_ldsx[16][512];

    for (int i = tid; i < 9 * 512; i += 256) w_lds[i >> 9][i & 511] = Wout[i];
    for (int i = tid; i < 16 * 128; i += 256) {
        const int bb = i >> 7; const int k = (i & 127) * 4;
        *reinterpret_cast<float4*>(&h_ldsx[bb][k]) =
            *reinterpret_cast<const float4*>(&h_hist[((size_t)(bg * 16 + bb) * 512 + l) * 512 + k]);
    }
    __syncthreads();

    const int bb = tid >> 4;
    const int j = tid & 15;
    if (j < 9) {
        float acc = bout[j];
        #pragma unroll 4
        for (int k = 0; k < 512; k += 4) {
            float4 hv = *reinterpret_cast<const float4*>(&h_ldsx[bb][k]);
            float4 wv = *reinterpret_cast<const float4*>(&w_lds[j][k]);
            acc += hv.x * wv.x + hv.y * wv.y + hv.z * wv.z + hv.w * wv.w;
        }
        em[((size_t)l * 64 + bg * 16 + bb) * 9 + j] = acc;
    }
}

__global__ __launch_bounds__(576) void viterbi_fwd(
    const float* __restrict__ em, const float* __restrict__ start,
    const float* __restrict__ trans, const float* __restrict__ endt,
    unsigned char* __restrict__ hist, int* __restrict__ last_tag,
    float* __restrict__ out_best)
{
    const int tid = threadIdx.x;
    const int b = tid / 9;
    const int j = tid - b * 9;
    __shared__ float sc[2][64][9];
    float t9[9];
    #pragma unroll
    for (int i = 0; i < 9; ++i) t9[i] = trans[i * 9 + j];

    sc[0][b][j] = start[j] + em[tid];
    float emv = em[(64 + b) * 9 + j];          // em for t=1
    __syncthreads();
    for (int t = 1; t < 512; ++t) {
        float em_nxt = (t < 511) ? em[((t + 1) * 64 + b) * 9 + j] : 0.f;  // prefetch
        const int cur = t & 1, prv = cur ^ 1;
        float best = -1e30f; int arg = 0;
        #pragma unroll
        for (int i = 0; i < 9; ++i) {
            float v = sc[prv][b][i] + t9[i];
            if (v > best) { best = v; arg = i; }
        }
        best += emv;
        sc[cur][b][j] = best;
        hist[((size_t)b * 512 + t) * 9 + j] = (unsigned char)arg;
        __syncthreads();
        emv = em_nxt;
    }
    sc[1][b][j] += endt[j];
    __syncthreads();
    if (j == 0) {
        float best = -1e30f; int arg = 0;
        #pragma unroll
        for (int i = 0; i < 9; ++i) {
            float v = sc[1][b][i];
            if (v > best) { best = v; arg = i; }
        }
        out_best[b] = best;
        last_tag[b] = arg;
    }
}

__global__ __launch_bounds__(256) void backtrack(
    const unsigned char* __restrict__ hist, const int* __restrict__ last_tag,
    float* __restrict__ out_tags)
{
    const int b = blockIdx.x;
    const int tid = threadIdx.x;
    __shared__ __align__(16) unsigned char hl[512 * 9];
    const uint4* src = reinterpret_cast<const uint4*>(hist + (size_t)b * 512 * 9);
    uint4* dst = reinterpret_cast<uint4*>(hl);
    for (int i = tid; i < 512 * 9 / 16; i += 256) dst[i] = src[i];
    __syncthreads();
    if (tid == 0) {
        int tag = last_tag[b];
        out_tags[b * 512 + 511] = (float)tag;
        for (int t = 511; t >= 1; --t) {
            tag = hl[t * 9 + tag];
            out_tags[b * 512 + t - 1] = (float)tag;
        }
    }
}

extern "C" void kernel_launch(void* const* d_in, const int* in_sizes, int n_in,
                              void* d_out, int out_size, void* d_ws, size_t ws_size,
                              hipStream_t stream)
{
    const int*   x     = (const int*)d_in[0];
    const float* embed = (const float*)d_in[1];
    const float* Wih_f = (const float*)d_in[2];
    const float* Whh_f = (const float*)d_in[3];
    const float* bf    = (const float*)d_in[4];
    const float* Wih_b = (const float*)d_in[5];
    const float* Whh_b = (const float*)d_in[6];
    const float* bb    = (const float*)d_in[7];
    const float* Wout  = (const float*)d_in[8];
    const float* bout  = (const float*)d_in[9];
    const float* start = (const float*)d_in[10];
    const float* trans = (const float*)d_in[11];
    const float* endt  = (const float*)d_in[12];

    char* ws = (char*)d_ws;
    float* h_glob = (float*)ws;                                   // 262144 B
    int*   tags   = (int*)(ws + 262144);                          // 4096 B
    float* h_hist = (float*)(ws + 266240);                        // 67108864 B
    float* em     = (float*)(ws + 266240 + 67108864);             // 1179648 B
    int*   last_tag = (int*)(ws + 67375104 + 1179648);            // @68554752
    unsigned char* hist = (unsigned char*)(ws + 68554752 + 256);  // @68555008

    float* out = (float*)d_out;   // [64*512 tags][64 best], all f32

    hipMemsetAsync(tags, 0, 4096, stream);   // reset tags each call

    lstm_persist<<<256, 256, 0, stream>>>(x, embed, Wih_f, Whh_f, bf,
                                          Wih_b, Whh_b, bb,
                                          h_glob, tags, h_hist);
    emis_kernel<<<2048, 256, 0, stream>>>(h_hist, Wout, bout, em);
    viterbi_fwd<<<1, 576, 0, stream>>>(em, start, trans, endt, hist, last_tag, out + 64 * 512);
    backtrack<<<64, 256, 0, stream>>>(hist, last_tag, out);
}

// Round 7
// 2817.202 us; speedup vs baseline: 5.1363x; 1.0123x over previous
//
#include <hip/hip_runtime.h>
#include <math.h>

// NER BiLSTM-CRF on MI355X — persistent recurrence, per-wave release, 2 barriers/step.
// fp32 throughout (Viterbi argmax flips are fatal: tags threshold 4.82, range 0..8).
//
// ALL cross-block traffic (h_glob, tags) uses sc0 sc1 = SYSTEM scope. Round-6 lesson:
// on gfx950, sc1:sc0 encode scope (agent=sc1, system=sc0 sc1); sc0 alone is
// workgroup-ish scope and may be served from stale per-CU L1 -> poll livelock.
//
// 256 blocks, 1/CU (109 KB LDS -> guaranteed residency). g=bid&7 (sync group),
// ug=bid>>3 (unit group of 8 units), d=g>>2, bg=g&3 (16 batches).
//
// Release (per wave w, after SYNC_B + pointwise): h stores sc0sc1 -> s_waitcnt
// vmcnt(0) [wave-scoped] -> tag[ug][w]=tt+1 (plain sc0sc1 store). No block barrier.
// Acquire: each thread polls the dwordx4 of its producer's (block tid>>3) 4 wave
// tags, needs all >= tt, then loads its 64B h chunk (sc0sc1).
// Safety: tag tt+1 from wave w of Z  =>  Z passed SYNC_A/B of step tt  =>  all Z
// fills (reads of buf[par]) done -> WAR safe; wave w's stores drained -> RAW safe.
// All 256 consumer threads collectively poll all 32 producers before SYNC_A.
//
// ws: h_glob [8 g][2 par][256 u][16 b] f32  262144 B @ 0
//     tags   [8 g][32 ug][4 w] i32          4096 B   @ 262144
//     (gap: 1024 B, unused)                          @ 266240
//     h_hist [64 b][512 l][512 h] f32       67108864 @ 267264
//     em     [512][64][9] f32               1179648  @ 67376128
//     last_tag [64] i32                     256      @ 68555776
//     hist   [64][512][9] u8                294912   @ 68556032

#define Bv 64
#define Lv 512

__device__ __forceinline__ float sigmoidf_(float x) { return 1.0f / (1.0f + expf(-x)); }

__global__ __launch_bounds__(256, 1) void lstm_persist(
    const int* __restrict__ x, const float* __restrict__ embed,
    const float* __restrict__ Wih_f, const float* __restrict__ Whh_f, const float* __restrict__ bf,
    const float* __restrict__ Wih_b, const float* __restrict__ Whh_b, const float* __restrict__ bb_,
    float* __restrict__ h_glob, int* __restrict__ tags, float* __restrict__ h_hist)
{
    const int bid = blockIdx.x;
    const int g  = bid & 7;           // sync group
    const int d  = g >> 2;            // direction
    const int bg = g & 3;             // batch group (16 batches)
    const int ug = bid >> 3;          // unit group (8 units)
    const int tid = threadIdx.x;
    const int u0 = ug * 8;
    const int b0 = bg * 16;

    const float* Wih  = d ? Wih_b : Wih_f;
    const float* Whh  = d ? Whh_b : Whh_f;
    const float* bias = d ? bb_   : bf;

    // dot tiling: tid = ks*32 + tr*4 + tb (8 ksegs of K=32, 8 row-slots, 4 batch-slots)
    const int ks = tid >> 5;
    const int tr = (tid >> 2) & 7;
    const int tb = tid & 3;
    const int k0 = ks * 32;

    __shared__ float wih_lds[32][260];
    __shared__ float h_lds[2][16][260];
    __shared__ float emb_lds[2][16][260];
    __shared__ float parts[4][32][17];
    __shared__ float bias_lds[32];

    // ---- stage Wih slice to LDS ----
    {
        const int row = tid >> 3;     // 0..31
        const int seg = tid & 7;      // 32 floats each
        const int gq = row >> 3, j = row & 7;
        const float4* src = reinterpret_cast<const float4*>(
            Wih + ((size_t)(gq * 256 + u0 + j)) * 256 + seg * 32);
        float4* dst = reinterpret_cast<float4*>(&wih_lds[row][seg * 32]);
        #pragma unroll
        for (int q = 0; q < 8; ++q) dst[q] = src[q];
    }
    if (tid < 32) bias_lds[tid] = bias[(tid >> 3) * 256 + u0 + (tid & 7)];

    // ---- Whh slice to registers: rows {tr+8i}, k window [k0,k0+32) ----
    float4 whh[4][8];
    #pragma unroll
    for (int i = 0; i < 4; ++i) {
        const float* wr = Whh + ((size_t)(i * 256 + u0 + tr)) * 256 + k0;
        #pragma unroll
        for (int m = 0; m < 8; ++m) whh[i][m] = *reinterpret_cast<const float4*>(wr + 4 * m);
    }

    // prologue: stage embedding for step 0 into emb buffer 0
    {
        const int b = tid >> 4;
        const int cseg = tid & 15;
        const int t_eff0 = d ? (Lv - 1) : 0;
        const int xv = x[(b0 + b) * Lv + t_eff0];
        const float4* src = reinterpret_cast<const float4*>(embed + (size_t)xv * 256 + cseg * 16);
        float4* dstp = reinterpret_cast<float4*>(&emb_lds[0][b][cseg * 16]);
        dstp[0] = src[0]; dstp[1] = src[1]; dstp[2] = src[2]; dstp[3] = src[3];
    }
    __syncthreads();

    float creg = 0.f;     // c for even threads: p=tid>>1 -> unit u0+(p&7), batch b0+(p>>3)
    const int* my_tags = tags + ((g * 32 + (tid >> 3)) << 2);
    int* rel_tag = tags + ((g * 32 + ug) << 2) + (tid >> 6);

    for (int tt = 0; tt < Lv; ++tt) {
        const int par = tt & 1;

        float acc[4][4];
        #pragma unroll
        for (int i = 0; i < 4; ++i)
            #pragma unroll
            for (int u = 0; u < 4; ++u) acc[i][u] = 0.f;

        // ---- 1. gx dot: Wih(lds) . emb(lds[par]) ----
        #pragma unroll
        for (int m = 0; m < 8; ++m) {
            float4 ev[4];
            #pragma unroll
            for (int u = 0; u < 4; ++u)
                ev[u] = *reinterpret_cast<const float4*>(&emb_lds[par][tb + 4 * u][k0 + 4 * m]);
            #pragma unroll
            for (int i = 0; i < 4; ++i) {
                float4 wv = *reinterpret_cast<const float4*>(&wih_lds[tr + 8 * i][k0 + 4 * m]);
                #pragma unroll
                for (int u = 0; u < 4; ++u)
                    acc[i][u] += wv.x * ev[u].x + wv.y * ev[u].y + wv.z * ev[u].z + wv.w * ev[u].w;
            }
        }

        // ---- 2. stage embedding for step tt+1 (overlaps the poll below) ----
        if (tt + 1 < Lv) {
            const int b = tid >> 4;
            const int cseg = tid & 15;
            const int t_eff1 = d ? (Lv - 2 - tt) : (tt + 1);
            const int xv = x[(b0 + b) * Lv + t_eff1];
            const float4* src = reinterpret_cast<const float4*>(embed + (size_t)xv * 256 + cseg * 16);
            float4 e0 = src[0], e1 = src[1], e2 = src[2], e3 = src[3];
            float4* dstp = reinterpret_cast<float4*>(&emb_lds[par ^ 1][b][cseg * 16]);
            dstp[0] = e0; dstp[1] = e1; dstp[2] = e2; dstp[3] = e3;
        }

        // ---- 3+4. poll producer tags (all 4 waves), fill own h chunk ----
        if (tt > 0) {
            int4 tv; int it = 0;
            for (;;) {
                asm volatile("global_load_dwordx4 %0, %1, off sc0 sc1\n\ts_waitcnt vmcnt(0)"
                             : "=v"(tv) : "v"(my_tags) : "memory");
                if (tv.x >= tt && tv.y >= tt && tv.z >= tt && tv.w >= tt) break;
                if (++it > 2) __builtin_amdgcn_s_sleep(2);
                if (it > (1 << 22)) break;   // failsafe (never hit when resident)
            }
            const float* hs = h_glob + ((size_t)(g * 2 + par)) * 4096 + tid * 16;
            float4 a0, a1, a2, a3;
            asm volatile(
                "global_load_dwordx4 %0, %4, off sc0 sc1\n\t"
                "global_load_dwordx4 %1, %4, off offset:16 sc0 sc1\n\t"
                "global_load_dwordx4 %2, %4, off offset:32 sc0 sc1\n\t"
                "global_load_dwordx4 %3, %4, off offset:48 sc0 sc1\n\t"
                "s_waitcnt vmcnt(0)"
                : "=v"(a0), "=v"(a1), "=v"(a2), "=v"(a3) : "v"(hs) : "memory");
            const int u = tid;
            h_lds[par][ 0][u] = a0.x; h_lds[par][ 1][u] = a0.y; h_lds[par][ 2][u] = a0.z; h_lds[par][ 3][u] = a0.w;
            h_lds[par][ 4][u] = a1.x; h_lds[par][ 5][u] = a1.y; h_lds[par][ 6][u] = a1.z; h_lds[par][ 7][u] = a1.w;
            h_lds[par][ 8][u] = a2.x; h_lds[par][ 9][u] = a2.y; h_lds[par][10][u] = a2.z; h_lds[par][11][u] = a2.w;
            h_lds[par][12][u] = a3.x; h_lds[par][13][u] = a3.y; h_lds[par][14][u] = a3.z; h_lds[par][15][u] = a3.w;
        }
        __syncthreads();   // SYNC_A: h_lds[par] ready, emb_lds[par^1] ready

        // ---- 5. hh dot: Whh(reg) . h(lds[par]) ----
        if (tt > 0) {
            #pragma unroll
            for (int m = 0; m < 8; ++m) {
                float4 hv[4];
                #pragma unroll
                for (int u = 0; u < 4; ++u)
                    hv[u] = *reinterpret_cast<const float4*>(&h_lds[par][tb + 4 * u][k0 + 4 * m]);
                #pragma unroll
                for (int i = 0; i < 4; ++i) {
                    float4 wv = whh[i][m];
                    #pragma unroll
                    for (int u = 0; u < 4; ++u)
                        acc[i][u] += wv.x * hv[u].x + wv.y * hv[u].y + wv.z * hv[u].z + wv.w * hv[u].w;
                }
            }
        }

        // ---- 6. reduce ksegs: shfl pair, 4 wave-partials to LDS ----
        #pragma unroll
        for (int i = 0; i < 4; ++i)
            #pragma unroll
            for (int u = 0; u < 4; ++u)
                acc[i][u] += __shfl_xor(acc[i][u], 32);
        if ((tid & 32) == 0) {
            const int w = tid >> 6;
            #pragma unroll
            for (int i = 0; i < 4; ++i)
                #pragma unroll
                for (int u = 0; u < 4; ++u)
                    parts[w][tr + 8 * i][tb + 4 * u] = acc[i][u];
        }
        __syncthreads();   // SYNC_B

        // ---- 7. pointwise on even threads (spread over all 4 waves) ----
        float hval = 0.f;
        if (!(tid & 1)) {
            const int p  = tid >> 1;     // 0..127
            const int j  = p & 7;
            const int bb = p >> 3;       // wave w handles bb = w*4..w*4+3
            float gv[4];
            #pragma unroll
            for (int q = 0; q < 4; ++q) {
                const int r = q * 8 + j;
                gv[q] = parts[0][r][bb] + parts[1][r][bb] + parts[2][r][bb] + parts[3][r][bb]
                      + bias_lds[r];
            }
            creg = sigmoidf_(gv[1]) * creg + sigmoidf_(gv[0]) * tanhf(gv[2]);
            hval = sigmoidf_(gv[3]) * tanhf(creg);
            float* dst = h_glob + ((size_t)(g * 2 + (par ^ 1))) * 4096 + (u0 + j) * 16 + bb;
            asm volatile("global_store_dword %0, %1, off sc0 sc1"
                         :: "v"(dst), "v"(hval) : "memory");
        }
        // per-wave release: own wave's stores drained -> publish tag
        asm volatile("s_waitcnt vmcnt(0)" ::: "memory");
        if ((tid & 63) == 0) {
            int val = tt + 1;
            asm volatile("global_store_dword %0, %1, off sc0 sc1"
                         :: "v"(rel_tag), "v"(val) : "memory");
        }
        // h_hist store off the critical path (plain cached store)
        if (!(tid & 1)) {
            const int p  = tid >> 1;
            const int j  = p & 7;
            const int bb = p >> 3;
            const int t_eff = d ? (Lv - 1 - tt) : tt;
            h_hist[((size_t)(b0 + bb) * Lv + t_eff) * 512 + d * 256 + u0 + j] = hval;
        }
    }
}

// emissions: em[l][b][j] = dot(h_hist[b][l][:512], Wout[j]) + bout[j]
__global__ __launch_bounds__(256) void emis_kernel(
    const float* __restrict__ h_hist, const float* __restrict__ Wout,
    const float* __restrict__ bout, float* __restrict__ em)
{
    const int l  = blockIdx.x >> 2;
    const int bg = blockIdx.x & 3;
    const int tid = threadIdx.x;
    __shared__ float w_lds[9][516];
    __shared__ float h_ldsx[16][512];

    for (int i = tid; i < 9 * 512; i += 256) w_lds[i >> 9][i & 511] = Wout[i];
    for (int i = tid; i < 16 * 128; i += 256) {
        const int bb = i >> 7; const int k = (i & 127) * 4;
        *reinterpret_cast<float4*>(&h_ldsx[bb][k]) =
            *reinterpret_cast<const float4*>(&h_hist[((size_t)(bg * 16 + bb) * 512 + l) * 512 + k]);
    }
    __syncthreads();

    const int bb = tid >> 4;
    const int j = tid & 15;
    if (j < 9) {
        float acc = bout[j];
        #pragma unroll 4
        for (int k = 0; k < 512; k += 4) {
            float4 hv = *reinterpret_cast<const float4*>(&h_ldsx[bb][k]);
            float4 wv = *reinterpret_cast<const float4*>(&w_lds[j][k]);
            acc += hv.x * wv.x + hv.y * wv.y + hv.z * wv.z + hv.w * wv.w;
        }
        em[((size_t)l * 64 + bg * 16 + bb) * 9 + j] = acc;
    }
}

__global__ __launch_bounds__(576) void viterbi_fwd(
    const float* __restrict__ em, const float* __restrict__ start,
    const float* __restrict__ trans, const float* __restrict__ endt,
    unsigned char* __restrict__ hist, int* __restrict__ last_tag,
    float* __restrict__ out_best)
{
    const int tid = threadIdx.x;
    const int b = tid / 9;
    const int j = tid - b * 9;
    __shared__ float sc[2][64][9];
    float t9[9];
    #pragma unroll
    for (int i = 0; i < 9; ++i) t9[i] = trans[i * 9 + j];

    sc[0][b][j] = start[j] + em[tid];
    float emv = em[(64 + b) * 9 + j];
    __syncthreads();
    for (int t = 1; t < 512; ++t) {
        float em_nxt = (t < 511) ? em[((t + 1) * 64 + b) * 9 + j] : 0.f;
        const int cur = t & 1, prv = cur ^ 1;
        float best = -1e30f; int arg = 0;
        #pragma unroll
        for (int i = 0; i < 9; ++i) {
            float v = sc[prv][b][i] + t9[i];
            if (v > best) { best = v; arg = i; }
        }
        best += emv;
        sc[cur][b][j] = best;
        hist[((size_t)b * 512 + t) * 9 + j] = (unsigned char)arg;
        __syncthreads();
        emv = em_nxt;
    }
    sc[1][b][j] += endt[j];
    __syncthreads();
    if (j == 0) {
        float best = -1e30f; int arg = 0;
        #pragma unroll
        for (int i = 0; i < 9; ++i) {
            float v = sc[1][b][i];
            if (v > best) { best = v; arg = i; }
        }
        out_best[b] = best;
        last_tag[b] = arg;
    }
}

__global__ __launch_bounds__(256) void backtrack(
    const unsigned char* __restrict__ hist, const int* __restrict__ last_tag,
    float* __restrict__ out_tags)
{
    const int b = blockIdx.x;
    const int tid = threadIdx.x;
    __shared__ __align__(16) unsigned char hl[512 * 9];
    const uint4* src = reinterpret_cast<const uint4*>(hist + (size_t)b * 512 * 9);
    uint4* dst = reinterpret_cast<uint4*>(hl);
    for (int i = tid; i < 512 * 9 / 16; i += 256) dst[i] = src[i];
    __syncthreads();
    if (tid == 0) {
        int tag = last_tag[b];
        out_tags[b * 512 + 511] = (float)tag;
        for (int t = 511; t >= 1; --t) {
            tag = hl[t * 9 + tag];
            out_tags[b * 512 + t - 1] = (float)tag;
        }
    }
}

extern "C" void kernel_launch(void* const* d_in, const int* in_sizes, int n_in,
                              void* d_out, int out_size, void* d_ws, size_t ws_size,
                              hipStream_t stream)
{
    const int*   x     = (const int*)d_in[0];
    const float* embed = (const float*)d_in[1];
    const float* Wih_f = (const float*)d_in[2];
    const float* Whh_f = (const float*)d_in[3];
    const float* bf    = (const float*)d_in[4];
    const float* Wih_b = (const float*)d_in[5];
    const float* Whh_b = (const float*)d_in[6];
    const float* bb    = (const float*)d_in[7];
    const float* Wout  = (const float*)d_in[8];
    const float* bout  = (const float*)d_in[9];
    const float* start = (const float*)d_in[10];
    const float* trans = (const float*)d_in[11];
    const float* endt  = (const float*)d_in[12];

    char* ws = (char*)d_ws;
    float* h_glob  = (float*)ws;                        // 262144 B
    int*   tags    = (int*)(ws + 262144);               // 4096 B
    float* h_hist  = (float*)(ws + 267264);             // 67108864 B
    float* em      = (float*)(ws + 267264 + 67108864);  // @67376128, 1179648 B
    int*   last_tag = (int*)(ws + 68555776);            // 256 B
    unsigned char* hist = (unsigned char*)(ws + 68556032); // 294912 B

    float* out = (float*)d_out;   // [64*512 tags][64 best], all f32

    hipMemsetAsync(tags, 0, 4096, stream);        // tags = 0

    lstm_persist<<<256, 256, 0, stream>>>(x, embed, Wih_f, Whh_f, bf,
                                          Wih_b, Whh_b, bb,
                                          h_glob, tags, h_hist);
    emis_kernel<<<2048, 256, 0, stream>>>(h_hist, Wout, bout, em);
    viterbi_fwd<<<1, 576, 0, stream>>>(em, start, trans, endt, hist, last_tag, out + 64 * 512);
    backtrack<<<64, 256, 0, stream>>>(hist, last_tag, out);
}